// Round 10
// baseline (298.880 us; speedup 1.0000x reference)
//
#include <hip/hip_runtime.h>

// QuantAttnBlock on gfx950, round 10: attention pass2 m-split across blocks
// (512 blocks = 2 barrier-domains/CU), K/V double-buffer -> 2 barriers/mt,
// exact i32 partial-O + tiny reduce. Pass1 (sum-exp) back as its own
// 8-blocks/CU kernel.

#define Bb 4
#define Cc 256
#define Nn 4096
#define NGRP 32
#define LOG2E 1.4426950408889634f

typedef unsigned short u16;
typedef unsigned int   u32;
typedef unsigned char  u8;
typedef __attribute__((ext_vector_type(8))) short bf16x8;
typedef __attribute__((ext_vector_type(4))) float f32x4;
typedef __attribute__((ext_vector_type(4))) int   i32x4;

#define MFMA16(a,b,c)    __builtin_amdgcn_mfma_f32_16x16x32_bf16((a),(b),(c),0,0,0)
#define MFMA_I8(a,b,c)   __builtin_amdgcn_mfma_i32_16x16x64_i8((a),(b),(c),0,0,0)

static __device__ __forceinline__ u16 f2bf(float x){
  u32 u = __float_as_uint(x);
  u += 0x7fffu + ((u >> 16) & 1u);
  return (u16)(u >> 16);
}
static __device__ __forceinline__ float bf2f(u16 h){ return __uint_as_float(((u32)h) << 16); }

union U64c { u16 u[4]; uint2 v; };

// ---------------- GroupNorm stats ----------------
__global__ __launch_bounds__(256) void k_gn_stats(const float* __restrict__ x,
                                                  float* __restrict__ mu, float* __restrict__ rs){
  int bg = blockIdx.x;
  const float4* p = (const float4*)(x + (size_t)bg * (8 * Nn));
  float s = 0.f, q = 0.f;
  for (int i = threadIdx.x; i < 8*Nn/4; i += 256){
    float4 v = p[i];
    s += v.x + v.y + v.z + v.w;
    q += v.x*v.x + v.y*v.y + v.z*v.z + v.w*v.w;
  }
  __shared__ float rsum[256], rsq[256];
  rsum[threadIdx.x] = s; rsq[threadIdx.x] = q;
  __syncthreads();
  for (int off = 128; off > 0; off >>= 1){
    if (threadIdx.x < off){ rsum[threadIdx.x] += rsum[threadIdx.x+off]; rsq[threadIdx.x] += rsq[threadIdx.x+off]; }
    __syncthreads();
  }
  if (threadIdx.x == 0){
    const float inv = 1.0f / (8*Nn);
    float m = rsum[0]*inv;
    float var = rsq[0]*inv - m*m;
    mu[bg] = m; rs[bg] = rsqrtf(var + 1e-6f);
  }
}

// ------------- weight split: 4 matrices f32 -> hi/lo bf16 -------------
__global__ __launch_bounds__(256) void k_wsplit(const float* __restrict__ wq, const float* __restrict__ wk,
                                                const float* __restrict__ wv, const float* __restrict__ wp,
                                                u16* __restrict__ WH, u16* __restrict__ WL){
  int gid = blockIdx.x*256 + threadIdx.x;
  int mat = gid >> 16, idx = gid & 65535;
  const float* src = (mat == 0) ? wq : (mat == 1) ? wk : (mat == 2) ? wv : wp;
  float w = src[idx];
  u16 h = f2bf(w);
  WH[gid] = h;
  WL[gid] = f2bf(w - bf2f(h));
}

// ------------- GroupNorm apply + transpose -> hT hi/lo [b][n][c] -------------
__global__ __launch_bounds__(256) void k_gn_apply(const float* __restrict__ x,
                                                  const float* __restrict__ gsc, const float* __restrict__ gbi,
                                                  const float* __restrict__ mu, const float* __restrict__ rs,
                                                  u16* __restrict__ hhi, u16* __restrict__ hlo){
  int nt = blockIdx.x, ct = blockIdx.y, b = blockIdx.z;
  int n0 = nt*64, c0 = ct*64;
  __shared__ float yt[64*65];
  __shared__ float sa[64], sb[64];
  int t = threadIdx.x;
  if (t < 64){
    int c = c0 + t;
    int bg = b*NGRP + (c >> 3);
    float a = rs[bg] * gsc[c];
    sa[t] = a;
    sb[t] = gbi[c] - mu[bg]*a;
  }
  __syncthreads();
  #pragma unroll
  for (int j = 0; j < 4; ++j){
    int id = t + j*256;
    int r = id >> 4, cq = id & 15;
    float4 v = *(const float4*)(x + ((size_t)b*Cc + c0 + r)*Nn + n0 + cq*4);
    float a = sa[r], bb = sb[r];
    yt[r*65 + cq*4 + 0] = v.x*a + bb;
    yt[r*65 + cq*4 + 1] = v.y*a + bb;
    yt[r*65 + cq*4 + 2] = v.z*a + bb;
    yt[r*65 + cq*4 + 3] = v.w*a + bb;
  }
  __syncthreads();
  int nl = t >> 2, cg = (t & 3) * 16;
  size_t base = ((size_t)b*Nn + n0 + nl)*Cc + c0 + cg;
  #pragma unroll
  for (int half = 0; half < 2; ++half){
    union { u16 u[8]; uint4 v; } Ph, Pl;
    #pragma unroll
    for (int u = 0; u < 8; ++u){
      float y = yt[(cg + half*8 + u)*65 + nl];
      u16 h = f2bf(y);
      Ph.u[u] = h; Pl.u[u] = f2bf(y - bf2f(h));
    }
    *(uint4*)(hhi + base + half*8) = Ph.v;
    *(uint4*)(hlo + base + half*8) = Pl.v;
  }
}

// ------------- Fused QKV conv GEMM (bf16 hi/lo, ~fp32 accurate) -------------
__global__ __launch_bounds__(256) void k_convqkv(const u16* __restrict__ WH, const u16* __restrict__ WL,
                                                 const u16* __restrict__ Hhi, const u16* __restrict__ Hlo,
                                                 const float* __restrict__ bq, const float* __restrict__ bk,
                                                 const float* __restrict__ bv,
                                                 const float* __restrict__ dq, const float* __restrict__ zq,
                                                 const float* __restrict__ dk, const float* __restrict__ zk,
                                                 const float* __restrict__ dv, const float* __restrict__ zv,
                                                 u8* __restrict__ qT8, u8* __restrict__ kT8,
                                                 u8* __restrict__ v8){
  int nt = blockIdx.x, ot = blockIdx.y, b = blockIdx.z;
  __shared__ u16 Lh[64*256], Ll[64*256];
  int t = threadIdx.x, lane = t & 63, wave = t >> 6;
  int lo16 = lane & 15, quad = lane >> 4;
  int o0 = ot*64 + wave*16;

  {
    const u16* hb = Hhi + ((size_t)b*Nn + nt*64) * 256;
    const u16* lb = Hlo + ((size_t)b*Nn + nt*64) * 256;
    #pragma unroll
    for (int j = 0; j < 8; ++j){
      int id = t + j*256;
      int r = id >> 5, ch = id & 31;
      int sw = (ch ^ (r & 15)) * 8;
      *(uint4*)(Lh + r*256 + sw) = *(const uint4*)(hb + (size_t)r*256 + ch*8);
      *(uint4*)(Ll + r*256 + sw) = *(const uint4*)(lb + (size_t)r*256 + ch*8);
    }
  }
  __syncthreads();

  const float* Bs[3] = {bq, bk, bv};
  const float* Dsr[3] = {dq, dk, dv};
  const float* Zs[3] = {zq, zk, zv};

  #pragma unroll
  for (int ws = 0; ws < 3; ++ws){
    bf16x8 awh[8], awl[8];
    {
      const u16* wbh = WH + (size_t)ws*65536 + (size_t)(o0 + lo16) * 256 + quad*8;
      const u16* wbl = WL + (size_t)ws*65536 + (size_t)(o0 + lo16) * 256 + quad*8;
      #pragma unroll
      for (int k = 0; k < 8; ++k){
        awh[k] = *(const bf16x8*)(wbh + k*32);
        awl[k] = *(const bf16x8*)(wbl + k*32);
      }
    }
    f32x4 zf = {0.f,0.f,0.f,0.f};
    f32x4 acc[4] = {zf, zf, zf, zf};
    #pragma unroll
    for (int k = 0; k < 8; ++k){
      #pragma unroll
      for (int ns = 0; ns < 4; ++ns){
        int r = ns*16 + lo16;
        int ph = ((k*4 + quad) ^ (r & 15)) * 8;
        bf16x8 bh = *(const bf16x8*)(Lh + r*256 + ph);
        bf16x8 bl = *(const bf16x8*)(Ll + r*256 + ph);
        acc[ns] = MFMA16(awh[k], bh, acc[ns]);
        acc[ns] = MFMA16(awl[k], bh, acc[ns]);
        acc[ns] = MFMA16(awh[k], bl, acc[ns]);
      }
    }
    float bia[4];
    #pragma unroll
    for (int r = 0; r < 4; ++r) bia[r] = Bs[ws][o0 + quad*4 + r];
    float z = Zs[ws][0]; float invd = 1.0f / Dsr[ws][0];

    if (ws < 2){
      u8* outT = (ws == 0) ? qT8 : kT8;
      #pragma unroll
      for (int ns = 0; ns < 4; ++ns){
        int n = nt*64 + ns*16 + lo16;
        u32 w = 0;
        #pragma unroll
        for (int r = 0; r < 4; ++r){
          float v = acc[ns][r] + bia[r];
          float xq = fminf(fmaxf(rintf(v*invd) + z, 0.f), 255.f);
          int qi = (int)rintf(xq - z);
          w |= ((u32)(qi & 255)) << (8*r);
        }
        *(u32*)(outT + ((size_t)b*Nn + n)*Cc + o0 + quad*4) = w;
      }
    } else {
      #pragma unroll
      for (int ns = 0; ns < 4; ++ns){
        int n = nt*64 + ns*16 + lo16;
        #pragma unroll
        for (int r = 0; r < 4; ++r){
          float v = acc[ns][r] + bia[r];
          float xq = fminf(fmaxf(rintf(v*invd) + z, 0.f), 255.f);
          int qi = (int)rintf(xq - z);
          v8[((size_t)b*Cc + o0 + quad*4 + r)*Nn + n] = (u8)(qi & 255);
        }
      }
    }
  }
}

// ------------- proj conv + residual -> f32 out -------------
__global__ __launch_bounds__(256) void k_conv(const u16* __restrict__ WH, const u16* __restrict__ WL,
                                              const u16* __restrict__ Hh,
                                              const float* __restrict__ bias,
                                              const float* __restrict__ xres, float* __restrict__ outF){
  int nt = blockIdx.x, ot = blockIdx.y, b = blockIdx.z;
  __shared__ u16 Lh[64*128];
  int t = threadIdx.x, lane = t & 63, wave = t >> 6;
  int lo16 = lane & 15, quad = lane >> 4;
  int o0 = ot*64 + wave*16;

  bf16x8 awh[8], awl[8];
  {
    const u16* wbh = WH + (size_t)3*65536 + (size_t)(o0 + lo16) * 256 + quad*8;
    const u16* wbl = WL + (size_t)3*65536 + (size_t)(o0 + lo16) * 256 + quad*8;
    #pragma unroll
    for (int k = 0; k < 8; ++k){
      awh[k] = *(const bf16x8*)(wbh + k*32);
      awl[k] = *(const bf16x8*)(wbl + k*32);
    }
  }
  f32x4 zf = {0.f,0.f,0.f,0.f};
  f32x4 acc[4] = {zf, zf, zf, zf};

  const u16* hb = Hh + ((size_t)b*Nn + nt*64) * 256;
  for (int kc = 0; kc < 2; ++kc){
    __syncthreads();
    for (int id = t; id < 64*16; id += 256){
      int r = id >> 4, ch = id & 15;
      int sw = (ch ^ (r & 7)) * 8;
      *(uint4*)(Lh + r*128 + sw) = *(const uint4*)(hb + (size_t)r*256 + kc*128 + ch*8);
    }
    __syncthreads();
    #pragma unroll
    for (int k4 = 0; k4 < 4; ++k4){
      int k = kc*4 + k4;
      #pragma unroll
      for (int ns = 0; ns < 4; ++ns){
        int r = ns*16 + lo16;
        int ch = ((k4*4 + quad) ^ (r & 7)) * 8;
        bf16x8 bh = *(const bf16x8*)(Lh + r*128 + ch);
        acc[ns] = MFMA16(awh[k], bh, acc[ns]);
        acc[ns] = MFMA16(awl[k], bh, acc[ns]);
      }
    }
  }

  float bia[4];
  #pragma unroll
  for (int r = 0; r < 4; ++r) bia[r] = bias[o0 + quad*4 + r];
  #pragma unroll
  for (int ns = 0; ns < 4; ++ns){
    int n = nt*64 + ns*16 + lo16;
    #pragma unroll
    for (int r = 0; r < 4; ++r){
      size_t a = ((size_t)b*Cc + o0 + quad*4 + r)*Nn + n;
      outF[a] = xres[a] + acc[ns][r] + bia[r];
    }
  }
}

static __device__ __forceinline__ void stage64x256(u8* dst, const u8* __restrict__ src, int t){
  #pragma unroll
  for (int j = 0; j < 4; ++j){
    int id = t + j*256; int r = id >> 4, ch = id & 15;
    *(uint4*)(dst + r*256 + ((ch ^ (r & 15)) << 4)) = *(const uint4*)(src + r*256 + ch*16);
  }
}

// ------------- merged: row norm^2 max + vsum -------------
static __device__ __forceinline__ int sq4(u32 w){
  int s = 0;
  #pragma unroll
  for (int j = 0; j < 4; ++j){ int v = (int)((signed char)((w >> (8*j)) & 0xffu)); s += v*v; }
  return s;
}
static __device__ __forceinline__ int ssum4(u32 w){
  return ((int)(w << 24) >> 24) + ((int)(w << 16) >> 24) + ((int)(w << 8) >> 24) + ((int)w >> 24);
}
__global__ __launch_bounds__(256) void k_normvs(const u8* __restrict__ qT8, const u8* __restrict__ kT8,
                                                const u8* __restrict__ v8,
                                                u32* __restrict__ stat, int* __restrict__ vsum){
  if (blockIdx.x < 128){
    int gid = blockIdx.x*256 + threadIdx.x;
    int which = gid >> 14;
    int rid = gid & 16383;
    const u8* row = (which ? kT8 : qT8) + (size_t)rid * 256;
    u32 acc = 0;
    const uint4* p = (const uint4*)row;
    #pragma unroll
    for (int i = 0; i < 16; ++i){
      uint4 w = p[i];
      acc += (u32)(sq4(w.x) + sq4(w.y) + sq4(w.z) + sq4(w.w));
    }
    #pragma unroll
    for (int msk = 32; msk > 0; msk >>= 1){
      u32 o = (u32)__shfl_xor((int)acc, msk, 64);
      acc = acc > o ? acc : o;
    }
    if ((threadIdx.x & 63) == 0)
      atomicMax(&stat[which*4 + (rid >> 12)], acc);
  } else {
    int row = blockIdx.x - 128;
    uint4 w = *(const uint4*)(v8 + (size_t)row*Nn + threadIdx.x*16);
    int s = ssum4(w.x) + ssum4(w.y) + ssum4(w.z) + ssum4(w.w);
    #pragma unroll
    for (int msk = 1; msk < 64; msk <<= 1) s += __shfl_xor(s, msk, 64);
    __shared__ int r4[4];
    if ((threadIdx.x & 63) == 0) r4[threadIdx.x >> 6] = s;
    __syncthreads();
    if (threadIdx.x == 0) vsum[row] = r4[0] + r4[1] + r4[2] + r4[3];
  }
}

// ------------- sum-exp pass: Lp[b][mc][n] (8 blocks/CU) -------------
__global__ __launch_bounds__(256) void k_sumexp(const u8* __restrict__ qT8, const u8* __restrict__ kT8,
                                                const u32* __restrict__ stat,
                                                const float* __restrict__ pdq, const float* __restrict__ pdk,
                                                float* __restrict__ Lp){
  int nt = blockIdx.x, mc = blockIdx.y, b = blockIdx.z;
  __shared__ u8 Kt[64*256];
  int t = threadIdx.x, lane = t & 63, wave = t >> 6;
  int lo16 = lane & 15, quad = lane >> 4;

  i32x4 a[4];
  {
    const u8* qb = qT8 + ((size_t)b*Nn + nt*64)*256;
    int ar = wave*16 + lo16;
    #pragma unroll
    for (int k = 0; k < 4; ++k)
      a[k] = *(const i32x4*)(qb + ar*256 + (k*4 + quad)*16);
  }
  float sc2 = pdq[0]*pdk[0]*0.0625f*LOG2E;
  float M2 = sc2 * sqrtf((float)stat[b] * (float)stat[4+b]);
  float lr[4] = {0.f,0.f,0.f,0.f};

  const u8* kbase = kT8 + ((size_t)b*Nn + mc*512)*256;
  for (int mt = 0; mt < 8; ++mt){
    __syncthreads();
    stage64x256(Kt, kbase + (size_t)mt*64*256, t);
    __syncthreads();
    #pragma unroll
    for (int ms = 0; ms < 4; ++ms){
      i32x4 acc = {0,0,0,0};
      int br = ms*16 + lo16;
      #pragma unroll
      for (int k = 0; k < 4; ++k){
        i32x4 bk_ = *(const i32x4*)(Kt + br*256 + (((k*4 + quad) ^ (br & 15)) << 4));
        acc = MFMA_I8(a[k], bk_, acc);
      }
      #pragma unroll
      for (int r = 0; r < 4; ++r)
        lr[r] += exp2f(fmaf((float)acc[r], sc2, -M2));
    }
  }
  #pragma unroll
  for (int msk = 1; msk < 16; msk <<= 1){
    #pragma unroll
    for (int r = 0; r < 4; ++r) lr[r] += __shfl_xor(lr[r], msk, 64);
  }
  if (lo16 == 0){
    #pragma unroll
    for (int r = 0; r < 4; ++r)
      Lp[((size_t)(b*8 + mc))*Nn + nt*64 + wave*16 + quad*4 + r] = lr[r];
  }
}

// ------------- pass2: QK -> quant -> Pt (LDS) -> PV, m-split x2, dbuf K/V,
// 2 barriers/mt, i32 partial O out. 512 blocks x 16 waves = 2 blocks/CU. -------------
__global__ __launch_bounds__(1024) void k_qpv2(const u8* __restrict__ qT8, const u8* __restrict__ kT8,
                                               const u8* __restrict__ v8,
                                               const u32* __restrict__ stat,
                                               const float* __restrict__ pdq, const float* __restrict__ pdk,
                                               const float* __restrict__ pdw, const float* __restrict__ pzw,
                                               const float* __restrict__ Lp,
                                               int* __restrict__ part){
  int nt = blockIdx.x, mh = blockIdx.y, b = blockIdx.z;
  __shared__ u8  Kt[2][64*256];
  __shared__ u8  Vt[2][256*64];
  __shared__ u32 Pt[64*16];
  int t = threadIdx.x, lane = t & 63, w = t >> 6;
  int lo16 = lane & 15, q = lane >> 4;
  int ms = w & 3, nsq = w >> 2;

  float sc2 = pdq[0]*pdk[0]*0.0625f*LOG2E;
  float M2 = sc2 * sqrtf((float)stat[b] * (float)stat[4+b]);
  float zw = pzw[0];

  int n = nt*64 + nsq*16 + lo16;
  i32x4 qf[4];
  {
    const u8* qb = qT8 + ((size_t)b*Nn + n)*256;
    #pragma unroll
    for (int kk = 0; kk < 4; ++kk)
      qf[kk] = *(const i32x4*)(qb + kk*64 + q*16);
  }
  float Ls = 0.f;
  #pragma unroll
  for (int mc = 0; mc < 8; ++mc) Ls += Lp[((size_t)(b*8 + mc))*Nn + n];
  float crn = __log2f(1.0f / (pdw[0] * Ls)) - M2;

  // staging indices
  int krow = t >> 4, kch = t & 15;
  int kdst = krow*256 + ((kch ^ (krow & 15)) << 4);
  const u8* kb = kT8 + ((size_t)b*Nn + mh*2048)*256;
  int vc = t >> 2, vch = t & 3;
  int vdst = vc*64 + ((vch ^ ((vc >> 1) & 3)) << 4);
  const u8* vrow = v8 + ((size_t)(b*Cc + vc))*Nn + mh*2048 + vch*16;

  int mrow = ms*16 + lo16;
  int kofs[4];
  #pragma unroll
  for (int kk = 0; kk < 4; ++kk) kofs[kk] = mrow*256 + (((kk*4 + q) ^ (mrow & 15)) << 4);
  int nrow = nsq*16 + lo16;
  int pdst = nrow*16 + ((ms ^ (nrow & 3) ^ ((nrow >> 2) & 3)) << 2) + q;
  int crv = w*16 + lo16;
  int vofs = crv*64 + ((q ^ ((crv >> 1) & 3)) << 4);
  int pofs[4];
  #pragma unroll
  for (int ns = 0; ns < 4; ++ns){
    int pr = ns*16 + lo16;
    pofs[ns] = pr*16 + ((q ^ (pr & 3) ^ ((pr >> 2) & 3)) << 2);
  }

  i32x4 zi = {0,0,0,0};
  i32x4 acc[4] = {zi,zi,zi,zi};

  uint4 kr = *(const uint4*)(kb + (size_t)krow*256 + kch*16);
  uint4 vr = *(const uint4*)(vrow);
  for (int mt = 0; mt < 32; ++mt){
    int buf = mt & 1;
    *(uint4*)(Kt[buf] + kdst) = kr;
    *(uint4*)(Vt[buf] + vdst) = vr;
    __syncthreads();                          // staging visible
    if (mt < 31){
      kr = *(const uint4*)(kb + (size_t)((mt+1)*64 + krow)*256 + kch*16);
      vr = *(const uint4*)(vrow + (mt+1)*64);
    }
    i32x4 s = {0,0,0,0};
    #pragma unroll
    for (int kk = 0; kk < 4; ++kk)
      s = MFMA_I8(*(const i32x4*)(Kt[buf] + kofs[kk]), qf[kk], s);
    u32 wp = 0;
    #pragma unroll
    for (int r = 0; r < 4; ++r){
      float at = exp2f(fmaf((float)s[r], sc2, crn));
      float y = fminf(fmaxf(rintf(at) + zw, 0.f), 255.f);
      wp = __builtin_amdgcn_cvt_pk_u8_f32(y, (u32)r, wp);
    }
    Pt[pdst] = wp ^ 0x80808080u;
    __syncthreads();                          // Pt ready
    i32x4 af = *(const i32x4*)(Vt[buf] + vofs);
    #pragma unroll
    for (int ns = 0; ns < 4; ++ns)
      acc[ns] = MFMA_I8(af, *(const i32x4*)(Pt + pofs[ns]), acc[ns]);
  }

  int c0 = w*16 + q*4;
  int* pb = part + ((size_t)(mh*Bb + b)*Nn)*Cc;
  #pragma unroll
  for (int ns = 0; ns < 4; ++ns){
    int nn = nt*64 + ns*16 + lo16;
    *(i32x4*)(pb + (size_t)nn*Cc + c0) = acc[ns];
  }
}

// ------------- reduce partials + scale + zero-point corr -> h2 bf16 -------------
__global__ __launch_bounds__(256) void k_red(const int* __restrict__ part, const int* __restrict__ vsum,
                                             const float* __restrict__ pdv, const float* __restrict__ pdw,
                                             const float* __restrict__ pzw,
                                             u16* __restrict__ h2){
  size_t gid = (size_t)blockIdx.x*256 + threadIdx.x;   // over 4.19M/4
  size_t e0 = gid*4;
  i32x4 p0 = *(const i32x4*)(part + e0);
  i32x4 p1 = *(const i32x4*)(part + (size_t)Bb*Nn*Cc + e0);
  int c0 = (int)(e0 & 255);
  int b = (int)(e0 >> 20);
  float s = pdv[0] * pdw[0];
  float corr = s * (128.0f - pzw[0]);
  U64c Uh;
  #pragma unroll
  for (int r = 0; r < 4; ++r)
    Uh.u[r] = f2bf(s*(float)(p0[r] + p1[r]) + corr*(float)vsum[b*Cc + c0 + r]);
  *(uint2*)(h2 + e0) = Uh.v;
}

extern "C" void kernel_launch(void* const* d_in, const int* in_sizes, int n_in,
                              void* d_out, int out_size, void* d_ws, size_t ws_size,
                              hipStream_t stream){
  (void)in_sizes; (void)n_in; (void)out_size; (void)ws_size;
  const float* x   = (const float*)d_in[0];
  const float* gsc = (const float*)d_in[1];
  const float* gbi = (const float*)d_in[2];
  const float* wq  = (const float*)d_in[3];
  const float* bq  = (const float*)d_in[4];
  const float* wk  = (const float*)d_in[5];
  const float* bk  = (const float*)d_in[6];
  const float* wv  = (const float*)d_in[7];
  const float* bv  = (const float*)d_in[8];
  const float* wp  = (const float*)d_in[9];
  const float* bp  = (const float*)d_in[10];
  const float* dq  = (const float*)d_in[11];
  const float* zq  = (const float*)d_in[12];
  const float* dk  = (const float*)d_in[13];
  const float* zk  = (const float*)d_in[14];
  const float* dv  = (const float*)d_in[15];
  const float* zv  = (const float*)d_in[16];
  const float* dw  = (const float*)d_in[17];
  const float* zw  = (const float*)d_in[18];
  float* out = (float*)d_out;

  const size_t SZT = (size_t)Bb*Nn*Cc;      // 4,194,304
  u16* hT_hi = (u16*)d_ws;
  u16* hT_lo = hT_hi + SZT;
  u16* h2    = hT_lo + SZT;
  u8*  qT8   = (u8*)(h2 + SZT);
  u8*  kT8   = qT8 + SZT;
  u8*  v8    = kT8 + SZT;
  u16* WH    = (u16*)(v8 + SZT);
  u16* WL    = WH + 4*65536;
  float* mu  = (float*)(WL + 4*65536);
  float* rs  = mu + 128;
  u32*  stat = (u32*)(rs + 128);
  int*  vsum = (int*)(stat + 8);
  float* Lp  = (float*)(vsum + Bb*Cc);      // 16B-aligned (offset 5152 from mu)
  int*  part = (int*)(Lp + (size_t)Bb*8*Nn);

  k_gn_stats<<<dim3(Bb*NGRP), 256, 0, stream>>>(x, mu, rs);
  k_wsplit<<<dim3(1024), 256, 0, stream>>>(wq, wk, wv, wp, WH, WL);
  k_gn_apply<<<dim3(Nn/64, Cc/64, Bb), 256, 0, stream>>>(x, gsc, gbi, mu, rs, hT_hi, hT_lo);

  k_convqkv<<<dim3(Nn/64, 4, Bb), 256, 0, stream>>>(WH, WL, hT_hi, hT_lo,
                                                    bq, bk, bv, dq, zq, dk, zk, dv, zv,
                                                    qT8, kT8, v8);

  hipMemsetAsync(stat, 0, 8*sizeof(u32), stream);
  k_normvs<<<dim3(128 + Bb*Cc), 256, 0, stream>>>(qT8, kT8, v8, stat, vsum);
  k_sumexp<<<dim3(Nn/64, 8, Bb), 256, 0, stream>>>(qT8, kT8, stat, dq, dk, Lp);

  k_qpv2<<<dim3(Nn/64, 2, Bb), 1024, 0, stream>>>(qT8, kT8, v8, stat, dq, dk, dw, zw, Lp, part);
  k_red<<<dim3((int)(SZT/1024)), 256, 0, stream>>>(part, vsum, dv, dw, zw, h2);

  k_conv<<<dim3(Nn/64, 4, Bb), 256, 0, stream>>>(WH, WL, h2, bp, x, out);
}